// Round 2
// baseline (549.520 us; speedup 1.0000x reference)
//
#include <hip/hip_runtime.h>

// ---------- types ----------
typedef __attribute__((ext_vector_type(8))) short short8;     // 8 bf16 (4 VGPRs)
typedef __attribute__((ext_vector_type(4))) float floatx4;    // MFMA C/D
typedef __attribute__((ext_vector_type(4))) unsigned int uintx4;

// ---------- fp32 -> packed bf16x2 (RNE) ----------
#if __has_builtin(__builtin_amdgcn_cvt_pk_bf16_f32)
typedef __attribute__((ext_vector_type(2))) __bf16 bf16x2;
__device__ __forceinline__ unsigned int pk_bf16(float a, float b) {
  bf16x2 v = __builtin_amdgcn_cvt_pk_bf16_f32(a, b);
  return __builtin_bit_cast(unsigned int, v);
}
#else
__device__ __forceinline__ unsigned int bf16_1(float f) {
  unsigned int u = __builtin_bit_cast(unsigned int, f);
  return (u + 0x7fffu + ((u >> 16) & 1u)) >> 16;
}
__device__ __forceinline__ unsigned int pk_bf16(float a, float b) {
  return bf16_1(a) | (bf16_1(b) << 16);
}
#endif

#if __has_builtin(__builtin_amdgcn_rcpf)
#define FRCP(x) __builtin_amdgcn_rcpf(x)
#else
#define FRCP(x) (1.0f / (x))
#endif
#if __has_builtin(__builtin_amdgcn_rsqf)
#define FRSQ(x) __builtin_amdgcn_rsqf(x)
#else
#define FRSQ(x) (1.0f / sqrtf(x))
#endif

// Fragment conventions (verified, absmax 3.9e-3):
//   A-frag (16x16x32): lane(ln,quad) holds A[m=ln][k=quad*8+j], j=0..7
//   B-frag:            lane(ln,quad) holds B[n=ln][k=quad*8+j]  (B[k][n]=W[c][r][k], n=r*8+c)
//   C/D:               col=ln, row=quad*4+reg
// Bprep frag id: Fb = ((mod*8 + h)*24 + ks)*4 + nt, n16 = h*4+nt; frag = 64 lanes x 16B.

// ============================================================
// Prepass v3: LDS-transposed. One block per (mod, n16): reads 16 weight rows
// (48 KB) fully coalesced, transposes to B-fragment layout in LDS (padded,
// ~2-way conflicts), writes 24 KB of frags fully coalesced. Grid 96 x 256.
// ============================================================
__global__ __launch_bounds__(256) void prep_w(
    const float* __restrict__ Wi, const float* __restrict__ Wc, const float* __restrict__ Wd,
    const float* __restrict__ bi, const float* __restrict__ bc, const float* __restrict__ bd,
    uintx4* __restrict__ Bprep, float* __restrict__ biasPrep) {
  __shared__ uintx4 Lb[24 * 65];  // idx16 = ks*65 + (q*16 + i); +1 pad per ks row

  const int tid = threadIdx.x;
  const int b = blockIdx.x;          // 0..95
  const int mod = b >> 5;
  const int n16 = b & 31;
  const float* __restrict__ W = (mod == 0) ? Wi : ((mod == 1) ? Wc : Wd);

  const int i = tid >> 4;            // which of the 16 n-rows (i = n & 15)
  const int ct = tid & 15;           // chunk lane within row
  const int n = n16 * 16 + i;
  const int r = n >> 3;
  const int c = n & 7;
  const float* rowp = W + (size_t)(c * 64 + r) * 768;

#pragma unroll
  for (int j = 0; j < 12; ++j) {
    const int k0 = (j * 16 + ct) * 4;          // float offset in row, 16B granule
    float4 f = *(const float4*)(rowp + k0);
    const int ks = k0 >> 5;
    const int q = (k0 >> 3) & 3;
    const int hf = (k0 >> 2) & 1;
    unsigned long long w =
        ((unsigned long long)pk_bf16(f.z, f.w) << 32) | pk_bf16(f.x, f.y);
    ((unsigned long long*)Lb)[((ks * 65 + q * 16 + i) << 1) + hf] = w;
  }
  __syncthreads();

  // write-out: frag = ((mod*8+h)*24 + ks)*4 + nt ; fully coalesced
  const int fragBaseC = ((mod * 8 + (n16 >> 2)) * 24) * 4 + (n16 & 3);
#pragma unroll
  for (int v = 0; v < 6; ++v) {
    const int e = v * 256 + tid;     // 0..1535 = 24 frags x 64 lanes
    const int ks = e >> 6;
    const int l = e & 63;
    Bprep[(size_t)(fragBaseC + ks * 4) * 64 + l] = Lb[ks * 65 + l];
  }

  const int t = b * 256 + tid;
  if (t < 1536) {
    const int m2 = t >> 9;
    const int nn = t & 511;
    const float* bb = (m2 == 0) ? bi : ((m2 == 1) ? bc : bd);
    biasPrep[t] = bb[(nn & 7) * 64 + (nn >> 3)];
  }
}

// ============================================================
// Fused v3: K-split staging -> LDS 24 KB -> 4 blocks/CU (32 waves/CU, HW max).
// Per half: stage A[32][384] as bf16 frags (slot-XOR swizzled), barrier,
// 12-step barrier-free K-loop with 3-buffer prefetch; cross-half B prefetch.
// XCD-swizzled blockIdx so each XCD L2 serves ~1 mod's 768 KB of Bprep.
// ============================================================
#define LOADA(aa, kk)                                                        \
  {                                                                          \
    _Pragma("unroll") for (int mt = 0; mt < 2; ++mt)                         \
        aa[mt] = Afr[((kk) * 2 + mt) * 64 +                                  \
                     ((ln ^ (((kk) * 4 + quad) & 15)) + (quad << 4))];       \
  }

#define LOADB(bb, gg)                                                        \
  {                                                                          \
    _Pragma("unroll") for (int nt = 0; nt < 4; ++nt)                         \
        bb[nt] = bbase[(size_t)((gg) * 4 + nt) * 64];                        \
  }

#define COMP(aa, bb)                                                     \
  {                                                                      \
    _Pragma("unroll") for (int mt = 0; mt < 2; ++mt)                     \
    {                                                                    \
      short8 af = __builtin_bit_cast(short8, aa[mt]);                    \
      _Pragma("unroll") for (int nt = 0; nt < 4; ++nt)                   \
          acc[mt][nt] = __builtin_amdgcn_mfma_f32_16x16x32_bf16(         \
              af, __builtin_bit_cast(short8, bb[nt]), acc[mt][nt], 0, 0, \
              0);                                                        \
    }                                                                    \
  }

__global__ __launch_bounds__(512, 8) void caps_fused(
    const float* __restrict__ x0, const float* __restrict__ x1, const float* __restrict__ x2,
    const uintx4* __restrict__ Bprep, const float* __restrict__ biasPrep,
    float* __restrict__ out) {
  __shared__ unsigned long long As64[24 * 128];  // 24 frags x 64 slots x 16 B = 24 KB

  const int tid = threadIdx.x;
  // XCD-aware swizzle (1536 % 8 == 0 -> bijective): consecutive v on same XCD
  const int bx = blockIdx.x;
  const int v = (bx & 7) * 192 + (bx >> 3);
  const int mod = v >> 9;            // each XCD sees ~1.3 mods -> B stays L2-hot
  const int bm = v & 511;            // m-tile (32 rows)
  const float* __restrict__ X = (mod == 0) ? x0 : ((mod == 1) ? x1 : x2);

  const int lane = tid & 63;
  const int ln = lane & 15;
  const int quad = lane >> 4;
  const int wv = tid >> 6;  // wave id 0..7: owns h = wv (n16 = wv*4 + nt)

  const uintx4* Afr = (const uintx4*)As64;
  const uintx4* __restrict__ bbase =
      Bprep + (size_t)((mod * 8 + wv) * 24) * 4 * 64 + lane;
  const float* src = X + (size_t)bm * 32 * 768;

  floatx4 acc[2][4] = {};
  uintx4 a0[2], a1[2], a2[2], b0[4], b1[4], b2[4];

  // B prefetch for the first two steps: no LDS dependency, issue first
  LOADB(b0, 0);
  LOADB(b1, 1);

#pragma unroll
  for (int h2 = 0; h2 < 2; ++h2) {
    // ---- stage A half: 32 rows x 384 cols fp32 -> bf16 frags ----
#pragma unroll
    for (int i = 0; i < 6; ++i) {
      const int idx = i * 2048 + tid * 4;        // flat over [32][384]
      const int m = (unsigned)idx / 384u;
      const int kl = idx - m * 384;
      float4 f = *(const float4*)(src + (size_t)m * 768 + h2 * 384 + kl);
      const int ksl = kl >> 5;                   // local ks 0..11
      const int kk = kl & 31;
      const int qk = kk >> 3;
      const int jh = (kk >> 2) & 1;
      const int mt = m >> 4;
      const int lnn = m & 15;
      const int p = (ksl * 4 + qk) & 15;         // slot-XOR spread
      const int slot = (lnn ^ p) + (qk << 4);
      unsigned long long w =
          ((unsigned long long)pk_bf16(f.z, f.w) << 32) | pk_bf16(f.x, f.y);
      As64[(((ksl * 2 + mt) * 64 + slot) << 1) + jh] = w;
    }
    __syncthreads();

    const int g0 = h2 * 12;
    LOADA(a0, 0);
    LOADA(a1, 1);
#pragma unroll 1
    for (int s = 0; s < 9; s += 3) {
      LOADA(a2, s + 2);
      LOADB(b2, g0 + s + 2);
      COMP(a0, b0);                  // step s
      LOADA(a0, s + 3);
      LOADB(b0, g0 + s + 3);
      COMP(a1, b1);                  // step s+1
      LOADA(a1, s + 4);
      LOADB(b1, g0 + s + 4);
      COMP(a2, b2);                  // step s+2
    }
    LOADA(a2, 11);
    LOADB(b2, g0 + 11);
    COMP(a0, b0);                    // step 9
    if (h2 == 0) LOADB(b0, 12);      // cross-half prefetch
    COMP(a1, b1);                    // step 10
    if (h2 == 0) LOADB(b1, 13);
    COMP(a2, b2);                    // step 11
    if (h2 == 0) __syncthreads();    // protect LDS before restage
  }

  // ---- epilogue: bias + squash (8 consecutive n cols = 8 lanes) + store ----
  const int col0 = mod * 512 + wv * 64 + ln;
  float bias[4];
#pragma unroll
  for (int nt = 0; nt < 4; ++nt) bias[nt] = biasPrep[col0 + nt * 16];

#pragma unroll
  for (int mt = 0; mt < 2; ++mt) {
    const size_t rbase = (size_t)(bm * 32 + mt * 16 + quad * 4) * 1536;
#pragma unroll
    for (int nt = 0; nt < 4; ++nt) {
      float* op = out + rbase + col0 + nt * 16;
#pragma unroll
      for (int jj = 0; jj < 4; ++jj) {
        float u = acc[mt][nt][jj] + bias[nt];
        float s = u * u;
        s += __shfl_xor(s, 1);
        s += __shfl_xor(s, 2);
        s += __shfl_xor(s, 4);
        float sc = s * FRCP(1.0f + s) * FRSQ(s + 1e-7f);
        op[(size_t)jj * 1536] = u * sc;
      }
    }
  }
}

// ============================================================
extern "C" void kernel_launch(void* const* d_in, const int* in_sizes, int n_in,
                              void* d_out, int out_size, void* d_ws, size_t ws_size,
                              hipStream_t stream) {
  const float* ximg = (const float*)d_in[0];
  const float* xcapt = (const float*)d_in[1];
  const float* xdct = (const float*)d_in[2];
  const float* Wi = (const float*)d_in[3];
  const float* bi = (const float*)d_in[4];
  const float* Wc = (const float*)d_in[5];
  const float* bc = (const float*)d_in[6];
  const float* Wd = (const float*)d_in[7];
  const float* bd = (const float*)d_in[8];

  uintx4* Bprep = (uintx4*)d_ws;                           // 2.25 MiB
  float* biasPrep = (float*)((char*)d_ws + 2304 * 1024);   // 6 KiB

  hipLaunchKernelGGL(prep_w, dim3(96), dim3(256), 0, stream,
                     Wi, Wc, Wd, bi, bc, bd, Bprep, biasPrep);
  hipLaunchKernelGGL(caps_fused, dim3(1536), dim3(512), 0, stream,
                     ximg, xcapt, xdct, (const uintx4*)Bprep, biasPrep,
                     (float*)d_out);
}

// Round 3
// 271.299 us; speedup vs baseline: 2.0255x; 2.0255x over previous
//
#include <hip/hip_runtime.h>

// ---------- types ----------
typedef __attribute__((ext_vector_type(8))) short short8;     // 8 bf16 (4 VGPRs)
typedef __attribute__((ext_vector_type(4))) float floatx4;    // MFMA C/D
typedef __attribute__((ext_vector_type(4))) unsigned int uintx4;

// ---------- fp32 -> packed bf16x2 (RNE) ----------
#if __has_builtin(__builtin_amdgcn_cvt_pk_bf16_f32)
typedef __attribute__((ext_vector_type(2))) __bf16 bf16x2;
__device__ __forceinline__ unsigned int pk_bf16(float a, float b) {
  bf16x2 v = __builtin_amdgcn_cvt_pk_bf16_f32(a, b);
  return __builtin_bit_cast(unsigned int, v);
}
#else
__device__ __forceinline__ unsigned int bf16_1(float f) {
  unsigned int u = __builtin_bit_cast(unsigned int, f);
  return (u + 0x7fffu + ((u >> 16) & 1u)) >> 16;
}
__device__ __forceinline__ unsigned int pk_bf16(float a, float b) {
  return bf16_1(a) | (bf16_1(b) << 16);
}
#endif

#if __has_builtin(__builtin_amdgcn_rcpf)
#define FRCP(x) __builtin_amdgcn_rcpf(x)
#else
#define FRCP(x) (1.0f / (x))
#endif
#if __has_builtin(__builtin_amdgcn_rsqf)
#define FRSQ(x) __builtin_amdgcn_rsqf(x)
#else
#define FRSQ(x) (1.0f / sqrtf(x))
#endif

// Fragment conventions (verified, absmax 3.9e-3):
//   A-frag (16x16x32): lane(ln,quad) holds A[m=ln][k=quad*8+j], j=0..7
//   B-frag:            lane(ln,quad) holds B[n=ln][k=quad*8+j]  (B[k][n]=W[c][r][k], n=r*8+c)
//   C/D:               col=ln, row=quad*4+reg
// Bprep frag id: Fb = ((mod*8 + h)*24 + ks)*4 + nt, n16 = h*4+nt; frag = 64 lanes x 16B.

// ============================================================
// Prepass (v3, verified): LDS-transposed. One block per (mod, n16): reads 16
// weight rows (48 KB) fully coalesced, transposes in LDS, writes 24 KB of
// frags fully coalesced. Grid 96 x 256.
// ============================================================
__global__ __launch_bounds__(256) void prep_w(
    const float* __restrict__ Wi, const float* __restrict__ Wc, const float* __restrict__ Wd,
    const float* __restrict__ bi, const float* __restrict__ bc, const float* __restrict__ bd,
    uintx4* __restrict__ Bprep, float* __restrict__ biasPrep) {
  __shared__ uintx4 Lb[24 * 65];  // idx16 = ks*65 + (q*16 + i); +1 pad per ks row

  const int tid = threadIdx.x;
  const int b = blockIdx.x;          // 0..95
  const int mod = b >> 5;
  const int n16 = b & 31;
  const float* __restrict__ W = (mod == 0) ? Wi : ((mod == 1) ? Wc : Wd);

  const int i = tid >> 4;            // which of the 16 n-rows (i = n & 15)
  const int ct = tid & 15;           // chunk lane within row
  const int n = n16 * 16 + i;
  const int r = n >> 3;
  const int c = n & 7;
  const float* rowp = W + (size_t)(c * 64 + r) * 768;

#pragma unroll
  for (int j = 0; j < 12; ++j) {
    const int k0 = (j * 16 + ct) * 4;          // float offset in row, 16B granule
    float4 f = *(const float4*)(rowp + k0);
    const int ks = k0 >> 5;
    const int q = (k0 >> 3) & 3;
    const int hf = (k0 >> 2) & 1;
    unsigned long long w =
        ((unsigned long long)pk_bf16(f.z, f.w) << 32) | pk_bf16(f.x, f.y);
    ((unsigned long long*)Lb)[((ks * 65 + q * 16 + i) << 1) + hf] = w;
  }
  __syncthreads();

  // write-out: frag = ((mod*8+h)*24 + ks)*4 + nt ; fully coalesced
  const int fragBaseC = ((mod * 8 + (n16 >> 2)) * 24) * 4 + (n16 & 3);
#pragma unroll
  for (int v = 0; v < 6; ++v) {
    const int e = v * 256 + tid;     // 0..1535 = 24 frags x 64 lanes
    const int ks = e >> 6;
    const int l = e & 63;
    Bprep[(size_t)(fragBaseC + ks * 4) * 64 + l] = Lb[ks * 65 + l];
  }

  const int t = b * 256 + tid;
  if (t < 1536) {
    const int m2 = t >> 9;
    const int nn = t & 511;
    const float* bb = (m2 == 0) ? bi : ((m2 == 1) ? bc : bd);
    biasPrep[t] = bb[(nn & 7) * 64 + (nn >> 3)];
  }
}

// ============================================================
// Fused v4: round-1 structure (single 48 KB A-stage, 8 waves x 64 n-cols,
// (512,4) -> 16 waves/CU) but the 24-step K-loop is FULLY UNROLLED with an
// explicit depth-4 B / depth-2 A register pipeline (all indices compile-time
// constant -> no loop-carried collapse; target VGPR ~120 <= 128 cap).
// XCD-swizzled blockIdx: each XCD serves ~1 mod's 768 KB of Bprep from L2.
// ============================================================
#define LOADA(aa, kk)                                                        \
  {                                                                          \
    _Pragma("unroll") for (int mt = 0; mt < 2; ++mt)                         \
        aa[mt] = Afr[((kk) * 2 + mt) * 64 +                                  \
                     ((ln ^ (((kk) * 4 + quad) & 15)) + (quad << 4))];       \
  }

#define LOADB(bb, gg)                                                        \
  {                                                                          \
    _Pragma("unroll") for (int nt = 0; nt < 4; ++nt)                         \
        bb[nt] = bbase[(size_t)((gg) * 4 + nt) * 64];                        \
  }

#define COMP(aa, bb)                                                     \
  {                                                                      \
    _Pragma("unroll") for (int mt = 0; mt < 2; ++mt)                     \
    {                                                                    \
      short8 af = __builtin_bit_cast(short8, aa[mt]);                    \
      _Pragma("unroll") for (int nt = 0; nt < 4; ++nt)                   \
          acc[mt][nt] = __builtin_amdgcn_mfma_f32_16x16x32_bf16(         \
              af, __builtin_bit_cast(short8, bb[nt]), acc[mt][nt], 0, 0, \
              0);                                                        \
    }                                                                    \
  }

__global__ __launch_bounds__(512, 4) void caps_fused(
    const float* __restrict__ x0, const float* __restrict__ x1, const float* __restrict__ x2,
    const uintx4* __restrict__ Bprep, const float* __restrict__ biasPrep,
    float* __restrict__ out) {
  __shared__ unsigned long long As64[48 * 128];  // 48 frags x 64 slots x 16 B

  const int tid = threadIdx.x;
  // XCD-aware swizzle (1536 % 8 == 0 -> bijective): consecutive v on same XCD
  const int bx = blockIdx.x;
  const int v = (bx & 7) * 192 + (bx >> 3);
  const int mod = v >> 9;            // each XCD sees ~1 mod -> B stays L2-hot
  const int bm = v & 511;            // m-tile (32 rows)
  const float* __restrict__ X = (mod == 0) ? x0 : ((mod == 1) ? x1 : x2);

  const int lane = tid & 63;
  const int ln = lane & 15;
  const int quad = lane >> 4;
  const int wv = tid >> 6;  // wave id 0..7: owns h = wv (n16 = wv*4 + nt)

  const uintx4* Afr = (const uintx4*)As64;
  const uintx4* __restrict__ bbase =
      Bprep + (size_t)((mod * 8 + wv) * 24) * 4 * 64 + lane;
  const float* src = X + (size_t)bm * 32 * 768;

  floatx4 acc[2][4] = {};
  uintx4 a[2][2], b[4][4];

  // B prefetch for the first two steps: no LDS dependency, issue first
  LOADB(b[0], 0);
  LOADB(b[1], 1);

  // ---- one-shot staging: 32 rows x 768 cols fp32, coalesced ----
#pragma unroll
  for (int i = 0; i < 12; ++i) {
    const int idx = i * 2048 + tid * 4;          // flat float index in tile
    float4 f = *(const float4*)(src + idx);
    const int m = (unsigned)idx / 768u;
    const int k = idx - m * 768;
    const int ks = k >> 5;
    const int kk = k & 31;
    const int qk = kk >> 3;                      // quad of k
    const int jh = (kk >> 2) & 1;                // which 8-byte half
    const int mt = m >> 4;
    const int lnn = m & 15;
    const int p = (ks * 4 + qk) & 15;            // slot-XOR spread
    const int slot = (lnn ^ p) + (qk << 4);
    unsigned long long w =
        ((unsigned long long)pk_bf16(f.z, f.w) << 32) | pk_bf16(f.x, f.y);
    As64[(((ks * 2 + mt) * 64 + slot) << 1) + jh] = w;
  }
  __syncthreads();  // the ONLY barrier

  LOADB(b[2], 2);
  LOADB(b[3], 3);
  LOADA(a[0], 0);
  LOADA(a[1], 1);

  // ---- fully-unrolled, software-pipelined 24-step K-loop ----
#pragma unroll
  for (int s = 0; s < 24; ++s) {
    COMP(a[s & 1], b[s & 3]);
    if (s + 2 < 24) LOADA(a[s & 1], s + 2);      // reuse regs just consumed
    if (s + 4 < 24) LOADB(b[s & 3], s + 4);
  }

  // ---- epilogue: bias + squash (8 consecutive n cols = 8 lanes) + store ----
  const int col0 = mod * 512 + wv * 64 + ln;
  float bias[4];
#pragma unroll
  for (int nt = 0; nt < 4; ++nt) bias[nt] = biasPrep[col0 + nt * 16];

#pragma unroll
  for (int mt = 0; mt < 2; ++mt) {
    const size_t rbase = (size_t)(bm * 32 + mt * 16 + quad * 4) * 1536;
#pragma unroll
    for (int nt = 0; nt < 4; ++nt) {
      float* op = out + rbase + col0 + nt * 16;
#pragma unroll
      for (int jj = 0; jj < 4; ++jj) {
        float u = acc[mt][nt][jj] + bias[nt];
        float s = u * u;
        s += __shfl_xor(s, 1);
        s += __shfl_xor(s, 2);
        s += __shfl_xor(s, 4);
        float sc = s * FRCP(1.0f + s) * FRSQ(s + 1e-7f);
        op[(size_t)jj * 1536] = u * sc;
      }
    }
  }
}

// ============================================================
extern "C" void kernel_launch(void* const* d_in, const int* in_sizes, int n_in,
                              void* d_out, int out_size, void* d_ws, size_t ws_size,
                              hipStream_t stream) {
  const float* ximg = (const float*)d_in[0];
  const float* xcapt = (const float*)d_in[1];
  const float* xdct = (const float*)d_in[2];
  const float* Wi = (const float*)d_in[3];
  const float* bi = (const float*)d_in[4];
  const float* Wc = (const float*)d_in[5];
  const float* bc = (const float*)d_in[6];
  const float* Wd = (const float*)d_in[7];
  const float* bd = (const float*)d_in[8];

  uintx4* Bprep = (uintx4*)d_ws;                           // 2.25 MiB
  float* biasPrep = (float*)((char*)d_ws + 2304 * 1024);   // 6 KiB

  hipLaunchKernelGGL(prep_w, dim3(96), dim3(256), 0, stream,
                     Wi, Wc, Wd, bi, bc, bd, Bprep, biasPrep);
  hipLaunchKernelGGL(caps_fused, dim3(1536), dim3(512), 0, stream,
                     ximg, xcapt, xdct, (const uintx4*)Bprep, biasPrep,
                     (float*)d_out);
}

// Round 4
// 269.751 us; speedup vs baseline: 2.0371x; 1.0057x over previous
//
#include <hip/hip_runtime.h>

// ---------- types ----------
typedef __attribute__((ext_vector_type(8))) short short8;     // 8 bf16 (4 VGPRs)
typedef __attribute__((ext_vector_type(4))) float floatx4;    // MFMA C/D
typedef __attribute__((ext_vector_type(4))) unsigned int uintx4;

// ---------- fp32 -> packed bf16x2 (RNE) ----------
#if __has_builtin(__builtin_amdgcn_cvt_pk_bf16_f32)
typedef __attribute__((ext_vector_type(2))) __bf16 bf16x2;
__device__ __forceinline__ unsigned int pk_bf16(float a, float b) {
  bf16x2 v = __builtin_amdgcn_cvt_pk_bf16_f32(a, b);
  return __builtin_bit_cast(unsigned int, v);
}
#else
__device__ __forceinline__ unsigned int bf16_1(float f) {
  unsigned int u = __builtin_bit_cast(unsigned int, f);
  return (u + 0x7fffu + ((u >> 16) & 1u)) >> 16;
}
__device__ __forceinline__ unsigned int pk_bf16(float a, float b) {
  return bf16_1(a) | (bf16_1(b) << 16);
}
#endif

#if __has_builtin(__builtin_amdgcn_rcpf)
#define FRCP(x) __builtin_amdgcn_rcpf(x)
#else
#define FRCP(x) (1.0f / (x))
#endif
#if __has_builtin(__builtin_amdgcn_rsqf)
#define FRSQ(x) __builtin_amdgcn_rsqf(x)
#else
#define FRSQ(x) (1.0f / sqrtf(x))
#endif

// Fragment conventions (verified, absmax 3.9e-3):
//   A-frag (16x16x32): lane(ln,quad) holds A[m=ln][k=quad*8+j], j=0..7
//   B-frag:            lane(ln,quad) holds B[n=ln][k=quad*8+j]  (B[k][n]=W[c][r][k], n=r*8+c)
//   C/D:               col=ln, row=quad*4+reg
// Bprep frag id: Fb = ((mod*8 + h)*24 + ks)*4 + nt, n16 = h*4+nt; frag = 64 lanes x 16B.

// ============================================================
// Prepass (v3, verified): LDS-transposed. One block per (mod, n16): reads 16
// weight rows (48 KB) fully coalesced, transposes in LDS, writes 24 KB of
// frags fully coalesced. Grid 96 x 256.
// ============================================================
__global__ __launch_bounds__(256) void prep_w(
    const float* __restrict__ Wi, const float* __restrict__ Wc, const float* __restrict__ Wd,
    const float* __restrict__ bi, const float* __restrict__ bc, const float* __restrict__ bd,
    uintx4* __restrict__ Bprep, float* __restrict__ biasPrep) {
  __shared__ uintx4 Lb[24 * 65];  // idx16 = ks*65 + (q*16 + i); +1 pad per ks row

  const int tid = threadIdx.x;
  const int b = blockIdx.x;          // 0..95
  const int mod = b >> 5;
  const int n16 = b & 31;
  const float* __restrict__ W = (mod == 0) ? Wi : ((mod == 1) ? Wc : Wd);

  const int i = tid >> 4;            // which of the 16 n-rows (i = n & 15)
  const int ct = tid & 15;           // chunk lane within row
  const int n = n16 * 16 + i;
  const int r = n >> 3;
  const int c = n & 7;
  const float* rowp = W + (size_t)(c * 64 + r) * 768;

#pragma unroll
  for (int j = 0; j < 12; ++j) {
    const int k0 = (j * 16 + ct) * 4;          // float offset in row, 16B granule
    float4 f = *(const float4*)(rowp + k0);
    const int ks = k0 >> 5;
    const int q = (k0 >> 3) & 3;
    const int hf = (k0 >> 2) & 1;
    unsigned long long w =
        ((unsigned long long)pk_bf16(f.z, f.w) << 32) | pk_bf16(f.x, f.y);
    ((unsigned long long*)Lb)[((ks * 65 + q * 16 + i) << 1) + hf] = w;
  }
  __syncthreads();

  // write-out: frag = ((mod*8+h)*24 + ks)*4 + nt ; fully coalesced
  const int fragBaseC = ((mod * 8 + (n16 >> 2)) * 24) * 4 + (n16 & 3);
#pragma unroll
  for (int v = 0; v < 6; ++v) {
    const int e = v * 256 + tid;     // 0..1535 = 24 frags x 64 lanes
    const int ks = e >> 6;
    const int l = e & 63;
    Bprep[(size_t)(fragBaseC + ks * 4) * 64 + l] = Lb[ks * 65 + l];
  }

  const int t = b * 256 + tid;
  if (t < 1536) {
    const int m2 = t >> 9;
    const int nn = t & 511;
    const float* bb = (m2 == 0) ? bi : ((m2 == 1) ? bc : bd);
    biasPrep[t] = bb[(nn & 7) * 64 + (nn >> 3)];
  }
}

// ============================================================
// Fused v5: round-1 structure (48 KB A-stage, 8 waves x 64 n-cols, (512,4))
// but the B pipeline is INLINE-ASM global_load_dwordx4 with counted
// s_waitcnt vmcnt(8) + sched_barrier(0): depth-3 rotation (48 pinned VGPRs)
// the compiler cannot collapse. vmcnt never drains to 0 in the main loop.
// WAR safety: b[s%3] is reloaded only AFTER COMP(s) consumed it (SSA
// anti-dep). No other VMEM in the loop (bias hoisted pre-staging).
// ============================================================
#define LOADA(aa, kk)                                                        \
  {                                                                          \
    _Pragma("unroll") for (int mt = 0; mt < 2; ++mt)                         \
        aa[mt] = Afr[((kk) * 2 + mt) * 64 +                                  \
                     ((ln ^ (((kk) * 4 + quad) & 15)) + (quad << 4))];       \
  }

// 4 B-frags of one K-step: base + {0,1024,2048,3072} bytes
#define ASMB(bb, gg)                                                         \
  {                                                                          \
    const unsigned long long _ad = bAddr + (unsigned long long)(gg)*4096ull; \
    asm volatile("global_load_dwordx4 %0, %4, off\n\t"                       \
                 "global_load_dwordx4 %1, %4, off offset:1024\n\t"           \
                 "global_load_dwordx4 %2, %4, off offset:2048\n\t"           \
                 "global_load_dwordx4 %3, %4, off offset:3072"               \
                 : "=&v"(bb[0]), "=&v"(bb[1]), "=&v"(bb[2]), "=&v"(bb[3])    \
                 : "v"(_ad));                                                \
  }

#define WAITB(N)                                   \
  do {                                             \
    asm volatile("s_waitcnt vmcnt(" #N ")");       \
    __builtin_amdgcn_sched_barrier(0);             \
  } while (0)

#define COMP(aa, bb)                                                     \
  {                                                                      \
    _Pragma("unroll") for (int mt = 0; mt < 2; ++mt)                     \
    {                                                                    \
      short8 af = __builtin_bit_cast(short8, aa[mt]);                    \
      _Pragma("unroll") for (int nt = 0; nt < 4; ++nt)                   \
          acc[mt][nt] = __builtin_amdgcn_mfma_f32_16x16x32_bf16(         \
              af, __builtin_bit_cast(short8, bb[nt]), acc[mt][nt], 0, 0, \
              0);                                                        \
    }                                                                    \
  }

__global__ __launch_bounds__(512, 4) void caps_fused(
    const float* __restrict__ x0, const float* __restrict__ x1, const float* __restrict__ x2,
    const uintx4* __restrict__ Bprep, const float* __restrict__ biasPrep,
    float* __restrict__ out) {
  __shared__ unsigned long long As64[48 * 128];  // 48 frags x 64 slots x 16 B

  const int tid = threadIdx.x;
  // XCD-aware swizzle (1536 % 8 == 0 -> bijective): consecutive v on same XCD
  const int bx = blockIdx.x;
  const int v = (bx & 7) * 192 + (bx >> 3);
  const int mod = v >> 9;            // each XCD sees ~1 mod -> B stays L2-hot
  const int bm = v & 511;            // m-tile (32 rows)
  const float* __restrict__ X = (mod == 0) ? x0 : ((mod == 1) ? x1 : x2);

  const int lane = tid & 63;
  const int ln = lane & 15;
  const int quad = lane >> 4;
  const int wv = tid >> 6;  // wave id 0..7: owns h = wv (n16 = wv*4 + nt)

  const uintx4* Afr = (const uintx4*)As64;
  const uintx4* __restrict__ bbase =
      Bprep + (size_t)((mod * 8 + wv) * 24) * 4 * 64 + lane;
  const unsigned long long bAddr = (unsigned long long)bbase;
  const float* src = X + (size_t)bm * 32 * 768;

  floatx4 acc[2][4] = {};
  uintx4 a[2][2], b[3][4];

  // ---- prefetch B steps 0..2 (oldest in vmcnt queue; done by the barrier)
  ASMB(b[0], 0);
  ASMB(b[1], 1);
  ASMB(b[2], 2);

  // ---- bias hoisted: no stray VMEM inside the K-loop ----
  const int col0 = mod * 512 + wv * 64 + ln;
  float bias[4];
#pragma unroll
  for (int nt = 0; nt < 4; ++nt) bias[nt] = biasPrep[col0 + nt * 16];

  // ---- one-shot staging: 32 rows x 768 cols fp32, coalesced ----
#pragma unroll
  for (int i = 0; i < 12; ++i) {
    const int idx = i * 2048 + tid * 4;          // flat float index in tile
    float4 f = *(const float4*)(src + idx);
    const int m = (unsigned)idx / 768u;
    const int k = idx - m * 768;
    const int ks = k >> 5;
    const int kk = k & 31;
    const int qk = kk >> 3;                      // quad of k
    const int jh = (kk >> 2) & 1;                // which 8-byte half
    const int mt = m >> 4;
    const int lnn = m & 15;
    const int p = (ks * 4 + qk) & 15;            // slot-XOR spread
    const int slot = (lnn ^ p) + (qk << 4);
    unsigned long long w =
        ((unsigned long long)pk_bf16(f.z, f.w) << 32) | pk_bf16(f.x, f.y);
    As64[(((ks * 2 + mt) * 64 + slot) << 1) + jh] = w;
  }
  __syncthreads();  // the ONLY barrier (drains vmcnt -> prefetched B ready)

  LOADA(a[0], 0);
  LOADA(a[1], 1);

  // ---- 24-step K-loop, counted-vmcnt pipeline (never drains mid-loop) ----
#pragma unroll
  for (int s = 0; s < 24; ++s) {
    if (s <= 21) {
      WAITB(8);      // step-s loads retired; 8 newer stay in flight
    } else if (s == 22) {
      WAITB(4);
    } else {
      WAITB(0);
    }
    __builtin_amdgcn_s_setprio(1);
    COMP(a[s & 1], b[s % 3]);
    __builtin_amdgcn_s_setprio(0);
    if (s + 2 < 24) LOADA(a[s & 1], s + 2);      // reuse regs just consumed
    if (s + 3 < 24) ASMB(b[s % 3], s + 3);       // reload AFTER consumption
  }

  // ---- epilogue: bias + squash (8 consecutive n cols = 8 lanes) + store ----
#pragma unroll
  for (int mt = 0; mt < 2; ++mt) {
    const size_t rbase = (size_t)(bm * 32 + mt * 16 + quad * 4) * 1536;
#pragma unroll
    for (int nt = 0; nt < 4; ++nt) {
      float* op = out + rbase + col0 + nt * 16;
#pragma unroll
      for (int jj = 0; jj < 4; ++jj) {
        float u = acc[mt][nt][jj] + bias[nt];
        float s = u * u;
        s += __shfl_xor(s, 1);
        s += __shfl_xor(s, 2);
        s += __shfl_xor(s, 4);
        float sc = s * FRCP(1.0f + s) * FRSQ(s + 1e-7f);
        op[(size_t)jj * 1536] = u * sc;
      }
    }
  }
}

// ============================================================
extern "C" void kernel_launch(void* const* d_in, const int* in_sizes, int n_in,
                              void* d_out, int out_size, void* d_ws, size_t ws_size,
                              hipStream_t stream) {
  const float* ximg = (const float*)d_in[0];
  const float* xcapt = (const float*)d_in[1];
  const float* xdct = (const float*)d_in[2];
  const float* Wi = (const float*)d_in[3];
  const float* bi = (const float*)d_in[4];
  const float* Wc = (const float*)d_in[5];
  const float* bc = (const float*)d_in[6];
  const float* Wd = (const float*)d_in[7];
  const float* bd = (const float*)d_in[8];

  uintx4* Bprep = (uintx4*)d_ws;                           // 2.25 MiB
  float* biasPrep = (float*)((char*)d_ws + 2304 * 1024);   // 6 KiB

  hipLaunchKernelGGL(prep_w, dim3(96), dim3(256), 0, stream,
                     Wi, Wc, Wd, bi, bc, bd, Bprep, biasPrep);
  hipLaunchKernelGGL(caps_fused, dim3(1536), dim3(512), 0, stream,
                     ximg, xcapt, xdct, (const uintx4*)Bprep, biasPrep,
                     (float*)d_out);
}